// Round 16
// baseline (9413.472 us; speedup 1.0000x reference)
//
#include <hip/hip_runtime.h>
#include <hip/hip_bf16.h>

#define S_LEN 2048
#define BATCH 64
#define HID   512
#define GATES 2048   // 4*HID
#define DIN   512

typedef __attribute__((ext_vector_type(8))) short short8v;
typedef __attribute__((ext_vector_type(4))) float f32x4;
typedef __attribute__((ext_vector_type(4))) unsigned uint4v;

__device__ inline unsigned short f2bf(float f) {
  union { float f; unsigned u; } a; a.f = f;
  unsigned r = a.u + 0x7fffu + ((a.u >> 16) & 1u);
  return (unsigned short)(r >> 16);
}
__device__ inline float bf2f(unsigned short h) {
  union { unsigned u; float f; } a; a.u = ((unsigned)h) << 16; return a.f;
}

// ---------- kernel 1: split x (fp32) -> bf16 hi + lo ----------
__global__ __launch_bounds__(256) void k_split_x(const float* __restrict__ x,
                                                 unsigned short* __restrict__ xhi,
                                                 unsigned short* __restrict__ xlo) {
  const long total = (long)S_LEN * BATCH * DIN / 4;
  long i = (long)blockIdx.x * blockDim.x + threadIdx.x;
  const long stride = (long)gridDim.x * blockDim.x;
  for (; i < total; i += stride) {
    float4 v = ((const float4*)x)[i];
    ushort4 hv, lv;
    hv.x = f2bf(v.x); lv.x = f2bf(v.x - bf2f(hv.x));
    hv.y = f2bf(v.y); lv.y = f2bf(v.y - bf2f(hv.y));
    hv.z = f2bf(v.z); lv.z = f2bf(v.z - bf2f(hv.z));
    hv.w = f2bf(v.w); lv.w = f2bf(v.w - bf2f(hv.w));
    ((ushort4*)xhi)[i] = hv;
    ((ushort4*)xlo)[i] = lv;
  }
}

// ---------- kernel 2: weights -> bf16, bias sum ----------
__global__ __launch_bounds__(256) void k_prep_w(const float* __restrict__ Wih,
                                                const float* __restrict__ Whh,
                                                const float* __restrict__ bih,
                                                const float* __restrict__ bhh,
                                                unsigned short* __restrict__ WihB,
                                                unsigned short* __restrict__ WhhB,
                                                float* __restrict__ bias) {
  int i = blockIdx.x * 256 + threadIdx.x;
  if (i < GATES * DIN) {
    WihB[i] = f2bf(Wih[i]);
    WhhB[i] = f2bf(Whh[i]);
  }
  if (i < GATES) bias[i] = bih[i] + bhh[i];
}

// ---------- kernel 3: pre[t][u][b][gate] = x[t,b,:]·Wih[gate*512+u,:] + biases ----------
#define BM 128
#define BN 128
#define BK 32
#define LDSROW 40

__global__ __launch_bounds__(256) void k_gemm_pre(
    const unsigned short* __restrict__ A,   // WihB [2048][512]
    const unsigned short* __restrict__ Bh,  // xhi  [131072][512]
    const unsigned short* __restrict__ Bl,  // xlo
    const float* __restrict__ bias,
    unsigned short* __restrict__ pre)       // [S][512 u][64 b][4 gate] bf16
{
  __shared__ unsigned short As [BM * LDSROW];
  __shared__ unsigned short Bhs[BM * LDSROW];
  __shared__ unsigned short Bls[BM * LDSROW];

  const int tid  = threadIdx.x;
  const int lane = tid & 63;
  const int wave = tid >> 6;
  const int bm = blockIdx.x & 15;
  const int bn = blockIdx.x >> 4;
  const int wr = wave >> 1, wc = wave & 1;

  f32x4 acc[4][4];
  #pragma unroll
  for (int i = 0; i < 4; ++i)
    #pragma unroll
    for (int j = 0; j < 4; ++j) acc[i][j] = (f32x4){0.f, 0.f, 0.f, 0.f};

  const long arow0 = (long)bm * BM;
  const long brow0 = (long)bn * BN;

  for (int kt = 0; kt < DIN / BK; ++kt) {
    #pragma unroll
    for (int it = 0; it < 2; ++it) {
      int c = tid + it * 256;
      int row = c >> 2, kc = c & 3;
      int lbyte = row * (LDSROW * 2) + kc * 16;
      long ga = (arow0 + row) * 512 + kt * BK + kc * 8;
      long gb = (brow0 + row) * 512 + kt * BK + kc * 8;
      *(short8v*)((char*)As  + lbyte) = *(const short8v*)(A  + ga);
      *(short8v*)((char*)Bhs + lbyte) = *(const short8v*)(Bh + gb);
      *(short8v*)((char*)Bls + lbyte) = *(const short8v*)(Bl + gb);
    }
    __syncthreads();

    short8v a[4], bh[4], bl[4];
    #pragma unroll
    for (int mt = 0; mt < 4; ++mt) {
      int r = wr * 64 + mt * 16 + (lane & 15);
      a[mt] = *(const short8v*)((const char*)As + r * (LDSROW * 2) + (lane >> 4) * 16);
    }
    #pragma unroll
    for (int nt = 0; nt < 4; ++nt) {
      int r = wc * 64 + nt * 16 + (lane & 15);
      bh[nt] = *(const short8v*)((const char*)Bhs + r * (LDSROW * 2) + (lane >> 4) * 16);
      bl[nt] = *(const short8v*)((const char*)Bls + r * (LDSROW * 2) + (lane >> 4) * 16);
    }
    #pragma unroll
    for (int mt = 0; mt < 4; ++mt)
      #pragma unroll
      for (int nt = 0; nt < 4; ++nt) {
        acc[mt][nt] = __builtin_amdgcn_mfma_f32_16x16x32_bf16(a[mt], bh[nt], acc[mt][nt], 0, 0, 0);
        acc[mt][nt] = __builtin_amdgcn_mfma_f32_16x16x32_bf16(a[mt], bl[nt], acc[mt][nt], 0, 0, 0);
      }
    __syncthreads();
  }

  #pragma unroll
  for (int mt = 0; mt < 4; ++mt) {
    #pragma unroll
    for (int j = 0; j < 4; ++j) {
      int m = bm * BM + wr * 64 + mt * 16 + (lane >> 4) * 4 + j;
      int gate = m >> 9;
      int u    = m & 511;
      float bv = bias[m];
      #pragma unroll
      for (int nt = 0; nt < 4; ++nt) {
        int n = bn * BN + wc * 64 + nt * 16 + (lane & 15);
        int t = n >> 6, b = n & 63;
        pre[(((long)t * 512 + u) * 64 + b) * 4 + gate] = f2bf(acc[mt][nt][j] + bv);
      }
    }
  }
}

// ---------- kernel 4: persistent recurrence, speculative verified gather ----------
// r15 machine (64 blocks x 512 threads, 8 gate-complete tiles, W_hh 128KB LDS,
// swizzled ldsH, u64-tagged h = (2xbf16)<<32 | step, drain+syncthreads+flag)
// with ONE change: a SPECULATIVE coherent gather before the flag poll.
//  * Ordering lemma (from the drain): data is MALL-visible BEFORE the flag is
//    issued. So if a spec gather sees incomplete tags, the flag poll would
//    also have missed at that instant -> a failed spec costs ~nothing. If it
//    sees tags==t on the whole slice, causality is identical to observing all
//    16 flags (tags==t -> every block published t -> their t-1 gathers done ->
//    overwriting phase (t+1)&1 is safe) and the flag RT is skipped entirely.
//  * Self-synchronizing: late blocks (peers long done) always spec-hit and
//    catch up, shrinking straggler spread.
//  * Spec uses agent atomics (L1/L2-bypassing) -> stale lines can't defeat it.
//    Fallback: flag poll + validated atomic re-gather (the r15 proven path).
__global__ __launch_bounds__(512, 1) void k_lstm(
    const unsigned short* __restrict__ pre,   // [S][512][64][4] bf16
    const unsigned short* __restrict__ WhhB,  // [2048][512] bf16
    unsigned long long* __restrict__ hbuf,    // [2][64 b][256] u64 (2 units | tag)
    unsigned* __restrict__ flags,             // [4][16]
    float* __restrict__ out)                  // [S*B*H | h_f | c_f]
{
  __shared__ char lds[147456];
  char* ldsW = lds;            // 128KB [ct:8][ks:16][ke:4][r:16][16B]
  char* ldsH = lds + 131072;   // 16KB  [ke:4][b:16][slot:16][16B], slot=(ks^b)&15

  const int tid  = threadIdx.x;
  const int lane = tid & 63;
  const int wave = tid >> 6;          // 0..7 == tile ct
  const int q    = blockIdx.x >> 4;   // batch quad
  const int ublk = blockIdx.x & 15;   // unit 32-block

  // --- stage W tile into LDS (once): tile-row r -> (du = r>>2, gate = r&3) ---
  for (int c = tid; c < 8192; c += 512) {
    int ct2 = c >> 10, r6 = c & 1023;
    int ks = r6 >> 6, ke = (r6 >> 4) & 3, r = r6 & 15;
    long row = (long)(r & 3) * 512 + ublk * 32 + ct2 * 4 + (r >> 2);
    *(short8v*)(ldsW + c * 16) =
        *(const short8v*)(WhhB + row * 512 + ks * 32 + ke * 8);
  }
  __syncthreads();

  // gather assignment: thread stages 16 units (8 tagged u64, 64B) for one row
  const int gb  = tid >> 5;           // 0..15 (batch row staged)
  const int us  = tid & 31;           // 0..31
  const int gks = us >> 1;            // k-step (32 units)
  const int keh = us & 1;             // which 16-unit half

  // cell assignment: one cell per lane, tile ct = wave
  const int ct  = wave;
  const int b_c = lane & 15;
  const int duc = lane >> 4;
  const int b_g = q * 16 + b_c;
  const int u_g = ublk * 32 + ct * 4 + duc;

  float cst = 0.f;
  float heat = (float)tid * 1e-3f + 1.0f;

  #pragma unroll 1
  for (int t = 0; t < S_LEN; ++t) {
    // x-gates (8B, i/f/g/o contiguous) — issued before the gather, hides under it
    ushort4 pv = *(const ushort4*)(pre + (((long)t * 512 + u_g) * 64 + b_g) * 4);

    if (t > 0) {
      const unsigned long long* hb = hbuf + (t & 1) * (64 * 256)
                                   + (q * 16 + gb) * 256 + gks * 16 + keh * 8;
      const unsigned tg = (unsigned)t;
      unsigned long long w[8];

      // SPECULATIVE coherent gather: 8 agent-atomic u64 loads, tag-validated.
      // Hit -> flag RT skipped. Miss -> flag would have missed too (lemma).
      #pragma unroll
      for (int j = 0; j < 8; ++j)
        w[j] = __hip_atomic_load(hb + j, __ATOMIC_RELAXED, __HIP_MEMORY_SCOPE_AGENT);
      unsigned bad = 0;
      #pragma unroll
      for (int j = 0; j < 8; ++j) bad |= ((unsigned)w[j]) ^ tg;

      if (!__all(bad == 0)) {
        // fallback: flag discovery (1 dword/lane; own block exempt)
        {
          const unsigned* fp = &flags[q * 16 + (lane & 15)];
          while (true) {
            unsigned v = ((lane & 15) == ublk) ? 0xffffffffu
                       : __hip_atomic_load(fp, __ATOMIC_RELAXED, __HIP_MEMORY_SCOPE_AGENT);
            if (__all(v >= (unsigned)t)) break;
            #pragma unroll
            for (int z = 0; z < 8; ++z) heat = __builtin_fmaf(heat, 1.000001f, 1e-6f);
            asm volatile("" : "+v"(heat));
          }
        }
        asm volatile("" ::: "memory");
        // validated coherent re-gather (r13 race stays closed)
        while (true) {
          #pragma unroll
          for (int j = 0; j < 8; ++j)
            w[j] = __hip_atomic_load(hb + j, __ATOMIC_RELAXED, __HIP_MEMORY_SCOPE_AGENT);
          unsigned b2 = 0;
          #pragma unroll
          for (int j = 0; j < 8; ++j) b2 |= ((unsigned)w[j]) ^ tg;
          if (__all(b2 == 0)) break;
        }
      }

      // payload = hi32 of each u64 (2 packed bf16 units); 2 swizzled b128 writes
      char* hp = ldsH + gb * 256 + ((gks ^ gb) & 15) * 16;
      uint4v d0, d1;
      #pragma unroll
      for (int j = 0; j < 4; ++j) {
        d0[j] = (unsigned)(w[j]     >> 32);
        d1[j] = (unsigned)(w[4 + j] >> 32);
      }
      *(uint4v*)(hp + (keh * 2 + 0) * 4096) = d0;
      *(uint4v*)(hp + (keh * 2 + 1) * 4096) = d1;
    }

    // barrier #1: H tile ready (LDS-only drain)
    asm volatile("s_waitcnt lgkmcnt(0)" ::: "memory");
    __builtin_amdgcn_s_barrier();
    __builtin_amdgcn_sched_barrier(0);

    f32x4 sum = (f32x4){0.f, 0.f, 0.f, 0.f};
    if (t > 0) {
      f32x4 e0 = sum, e1 = sum;
      const char* wa = ldsW + ct * 16384 + (lane >> 4) * 256 + (lane & 15) * 16;
      const char* ha = ldsH + (lane >> 4) * 4096 + (lane & 15) * 256;
      const int bcol = lane & 15;
      #pragma unroll
      for (int ks = 0; ks < 16; ++ks) {
        short8v av = *(const short8v*)(wa + ks * 1024);               // W (A-op)
        short8v bv = *(const short8v*)(ha + ((ks ^ bcol) & 15) * 16); // h (B-op)
        if (ks & 1) e1 = __builtin_amdgcn_mfma_f32_16x16x32_bf16(av, bv, e1, 0, 0, 0);
        else        e0 = __builtin_amdgcn_mfma_f32_16x16x32_bf16(av, bv, e0, 0, 0, 0);
      }
      sum = e0 + e1;
    }

    // barrier #2: ldsH reads of step t done -> next staging may overwrite
    asm volatile("s_waitcnt lgkmcnt(0)" ::: "memory");
    __builtin_amdgcn_s_barrier();
    __builtin_amdgcn_sched_barrier(0);

    // cell update fully in-register: sum[0..3] = (i,f,g,o)
    float zi = sum[0] + bf2f(pv.x);
    float zf = sum[1] + bf2f(pv.y);
    float zg = sum[2] + bf2f(pv.z);
    float zo = sum[3] + bf2f(pv.w);
    float ii = 1.f / (1.f + __expf(-zi));
    float ff = 1.f / (1.f + __expf(-zf));
    float e1x = __expf(2.f * fminf(zg, 15.f));
    float gg = (e1x - 1.f) / (e1x + 1.f);
    float oo = 1.f / (1.f + __expf(-zo));
    float cn = ff * cst + ii * gg;
    float e2x = __expf(2.f * fminf(cn, 15.f));
    float tc = (e2x - 1.f) / (e2x + 1.f);
    float hv = oo * tc;
    cst = cn;

    // tagged publish: pair lanes pack 2 units + step tag into one u64 store
    {
      unsigned short h16 = f2bf(hv);
      unsigned prt = (unsigned)__shfl_xor((int)(unsigned)h16, 16);
      if (!(lane & 16)) {   // duc even: lo16 = unit u, hi16 = unit u+1
        unsigned payload = (unsigned)h16 | (prt << 16);
        unsigned long long w64 = ((unsigned long long)payload << 32)
                               | (unsigned)(t + 1);
        __hip_atomic_store(hbuf + ((t + 1) & 1) * (64 * 256) + b_g * 256
                               + ublk * 16 + ct * 2 + (duc >> 1),
                           w64, __ATOMIC_RELAXED, __HIP_MEMORY_SCOPE_AGENT);
      }
    }

    // release: drain h stores, then publish flag (fallback discovery path;
    // the drain also establishes the spec-gather ordering lemma)
    asm volatile("s_waitcnt vmcnt(0)" ::: "memory");
    __syncthreads();
    if (tid == 0)
      __hip_atomic_store(&flags[q * 16 + ublk], (unsigned)(t + 1),
                         __ATOMIC_RELAXED, __HIP_MEMORY_SCOPE_AGENT);

    // out stores AFTER flag publish: off the critical path
    out[(long)t * (BATCH * HID) + (long)b_g * HID + u_g] = hv;
    if (t == S_LEN - 1) {
      long fb = (long)S_LEN * (BATCH * HID);
      out[fb + (long)b_g * HID + u_g] = hv;
      out[fb + BATCH * HID + (long)b_g * HID + u_g] = cn;
    }
  }
}

extern "C" void kernel_launch(void* const* d_in, const int* in_sizes, int n_in,
                              void* d_out, int out_size, void* d_ws, size_t ws_size,
                              hipStream_t stream) {
  const float* x   = (const float*)d_in[0];
  const float* Wih = (const float*)d_in[1];
  const float* Whh = (const float*)d_in[2];
  const float* bih = (const float*)d_in[3];
  const float* bhh = (const float*)d_in[4];
  float* out = (float*)d_out;

  char* ws = (char*)d_ws;
  size_t off = 0;
  auto alloc = [&](size_t bytes) -> char* {
    char* p = ws + off;
    off += (bytes + 255) & ~(size_t)255;
    return p;
  };
  unsigned short*     xhi  = (unsigned short*)alloc((size_t)S_LEN * BATCH * DIN * 2);
  unsigned short*     xlo  = (unsigned short*)alloc((size_t)S_LEN * BATCH * DIN * 2);
  unsigned short*     preb = (unsigned short*)alloc((size_t)S_LEN * GATES * BATCH * 2);
  unsigned short*     WihB = (unsigned short*)alloc((size_t)GATES * DIN * 2);
  unsigned short*     WhhB = (unsigned short*)alloc((size_t)GATES * DIN * 2);
  float*              bias = (float*)alloc((size_t)GATES * 4);
  unsigned long long* hbuf = (unsigned long long*)alloc((size_t)2 * 64 * 256 * 8); // 256KB
  unsigned*           flg  = (unsigned*)alloc((size_t)4 * 16 * 4);

  // replay-safe: clear tags + flags every launch
  hipMemsetAsync(hbuf, 0, (size_t)2 * 64 * 256 * 8, stream);
  hipMemsetAsync(flg, 0, (size_t)4 * 16 * 4, stream);
  k_split_x<<<8192, 256, 0, stream>>>(x, xhi, xlo);
  k_prep_w<<<4096, 256, 0, stream>>>(Wih, Whh, bih, bhh, WihB, WhhB, bias);
  k_gemm_pre<<<16384, 256, 0, stream>>>(WihB, xhi, xlo, bias, preb);
  k_lstm<<<64, 512, 0, stream>>>(preb, WhhB, hbuf, flg, out);
}